// Round 5
// baseline (310.225 us; speedup 1.0000x reference)
//
#include <hip/hip_runtime.h>

// TensorTrain: out[b] = first(x0) . M0(x1) . ... . M29(x30) . last(x31)
// R=16, D=32, B=262144, bits in {0,1}.
// Meet-in-the-middle: V16[p=x0..x15] row-vector, W16[s=x16..x31] col-vector,
// out = V16[p] . W16[s].
// R5: single plain kernel (512 blocks), phases A/B/C separated by a MANUAL
// device-scope spin barrier (cooperative launch silently failed in R4).
// Co-residency guaranteed: __launch_bounds__(256,2) => >=2 blocks/CU => all
// 512 blocks resident on 256 CUs. Barrier state lives in ws, zeroed by a
// hipMemsetAsync node each call (ws is re-poisoned to 0xAA by the harness).

#define R 16
#define TT_D 32
#define BATCH 262144
#define NBLK 512

// workspace layout, in floats
#define OFF_V8   0                      // 256 x 16     first + cores 0..6   (x0..x7)  row-vectors
#define OFF_P8   (OFF_V8 + 4096)        // 256 x 256    cores 7..14          (x8..x15) 16x16 row-major
#define OFF_Q8   (OFF_P8 + 65536)       // 256 x 256    cores 15..22         (x16..x23)
#define OFF_W8   (OFF_Q8 + 65536)       // 256 x 16     cores 23..29 + last  (x24..x31) col-vectors
#define OFF_V16  (OFF_W8 + 4096)        // 65536 x 16   prefix row-vectors
#define OFF_W16  (OFF_V16 + 1048576)    // 65536 x 16   suffix col-vectors
#define OFF_BAR  (OFF_W16 + 1048576)    // 16 uints barrier state (cnt, gen, ...)
#define WS_FLOATS (OFF_BAR + 16)

typedef int   v4i __attribute__((ext_vector_type(4)));
typedef float v4f __attribute__((ext_vector_type(4)));
typedef float v2f __attribute__((ext_vector_type(2)));

__device__ __forceinline__ void grid_barrier(unsigned* cnt, unsigned* gen) {
    __syncthreads();
    if (threadIdx.x == 0) {
        __threadfence();                                   // release table writes (device scope)
        const unsigned g0 = __hip_atomic_load(gen, __ATOMIC_RELAXED, __HIP_MEMORY_SCOPE_AGENT);
        const unsigned prev = __hip_atomic_fetch_add(cnt, 1u, __ATOMIC_ACQ_REL, __HIP_MEMORY_SCOPE_AGENT);
        if (prev == (unsigned)(NBLK - 1)) {
            __hip_atomic_store(cnt, 0u, __ATOMIC_RELAXED, __HIP_MEMORY_SCOPE_AGENT);
            __hip_atomic_fetch_add(gen, 1u, __ATOMIC_ACQ_REL, __HIP_MEMORY_SCOPE_AGENT);
        } else {
            while (__hip_atomic_load(gen, __ATOMIC_ACQUIRE, __HIP_MEMORY_SCOPE_AGENT) == g0) {
                __builtin_amdgcn_s_sleep(8);
            }
        }
        __threadfence();                                   // acquire side
    }
    __syncthreads();
}

__global__ __launch_bounds__(256, 2) void tt_all(const int* __restrict__ X,
                                                 const float* __restrict__ cf,
                                                 const float* __restrict__ cm,
                                                 const float* __restrict__ cl,
                                                 float* __restrict__ ws,
                                                 float* __restrict__ out) {
    __shared__ float sA[256], sB[256];
    const int g = blockIdx.x;
    const int t = threadIdx.x;
    unsigned* bar = (unsigned*)(ws + OFF_BAR);

    // ---------------- Phase A: byte tables (verified logic == R3 tt_byte_build) ----
    {
        const bool isP = (g < 256);
        const int e = g & 255;
        const int base = isP ? 7 : 15;
        const int r = t >> 4, s = t & 15;
        float acc = 0.f;
        sA[t] = cm[base * 512 + r * 32 + s * 2 + ((e >> 7) & 1)];
        float* cur = sA; float* nxt = sB;
        for (int j = 1; j < 8; j++) {
            __syncthreads();
            const int b = (e >> (7 - j)) & 1;
            const float* M = cm + (base + j) * 512 + b;    // (k,s) at M[k*32+s*2]
            acc = 0.f;
            #pragma unroll
            for (int k = 0; k < 16; k++)
                acc += cur[r * 16 + k] * M[k * 32 + s * 2];
            nxt[t] = acc;
            float* tmp = cur; cur = nxt; nxt = tmp;
        }
        ws[(isP ? OFF_P8 : OFF_Q8) + (e << 8) + t] = acc;

        if (isP && e < 16) {
            // V8 entries E = e*16 + el; thread t = (el<<4)|sv
            __syncthreads();
            const int el = t >> 4, sv = t & 15;
            const int E = e * 16 + el;
            float a2 = 0.f;
            sA[t] = cf[sv * 2 + ((E >> 7) & 1)];
            cur = sA; nxt = sB;
            for (int j = 0; j < 7; j++) {
                __syncthreads();
                const int b = (E >> (6 - j)) & 1;
                const float* M = cm + j * 512 + b;         // (r2,sv) at M[r2*32+sv*2]
                a2 = 0.f;
                #pragma unroll
                for (int r2 = 0; r2 < 16; r2++)
                    a2 += cur[el * 16 + r2] * M[r2 * 32 + sv * 2];
                nxt[t] = a2;
                float* tmp = cur; cur = nxt; nxt = tmp;
            }
            ws[OFF_V8 + e * 256 + t] = a2;                 // = E*16 + sv
        } else if (!isP && e < 16) {
            // W8 entries E = e*16 + el; thread t = (el<<4)|rv (col-vector, back-to-front)
            __syncthreads();
            const int el = t >> 4, rv = t & 15;
            const int E = e * 16 + el;
            float a2 = 0.f;
            sA[t] = cl[rv * 2 + (E & 1)];
            cur = sA; nxt = sB;
            for (int j = 0; j < 7; j++) {
                __syncthreads();
                const int c = 29 - j;
                const int b = (E >> (1 + j)) & 1;
                const float* M = cm + c * 512 + b;         // (rv,k) at M[rv*32+k*2]
                a2 = 0.f;
                #pragma unroll
                for (int k = 0; k < 16; k++)
                    a2 += M[rv * 32 + k * 2] * cur[el * 16 + k];
                nxt[t] = a2;
                float* tmp = cur; cur = nxt; nxt = tmp;
            }
            ws[OFF_W8 + e * 256 + t] = a2;
        }
    }

    grid_barrier(bar, bar + 1);

    // ---------------- Phase B: 16-bit tables (verified logic == R3 tt_tab) ----
    if (g < 256) {
        const int l = g;
        sA[t] = ws[OFF_P8 + (l << 8) + t];
        __syncthreads();
        const int h = t;
        const float* v8 = ws + OFF_V8 + (h << 4);
        float v[16];
        #pragma unroll
        for (int k = 0; k < 16; k++) v[k] = v8[k];
        float o[16];
        #pragma unroll
        for (int s = 0; s < 16; s++) o[s] = 0.f;
        #pragma unroll
        for (int r = 0; r < 16; r++) {
            const float a = v[r];
            #pragma unroll
            for (int s = 0; s < 16; s++) o[s] += a * sA[r * 16 + s];
        }
        float* dst = ws + OFF_V16 + ((size_t)((h << 8) | l) << 4);
        #pragma unroll
        for (int s = 0; s < 16; s++) dst[s] = o[s];
    } else {
        const int h = g - 256;
        sA[t] = ws[OFF_Q8 + (h << 8) + t];
        __syncthreads();
        const int l = t;
        const float* w8 = ws + OFF_W8 + (l << 4);
        float w[16];
        #pragma unroll
        for (int k = 0; k < 16; k++) w[k] = w8[k];
        float o[16];
        #pragma unroll
        for (int r = 0; r < 16; r++) {
            float acc = 0.f;
            #pragma unroll
            for (int k = 0; k < 16; k++) acc += sA[r * 16 + k] * w[k];
            o[r] = acc;
        }
        float* dst = ws + OFF_W16 + ((size_t)((h << 8) | l) << 4);
        #pragma unroll
        for (int r = 0; r < 16; r++) dst[r] = o[r];
    }

    grid_barrier(bar, bar + 1);

    // ---------------- Phase C: gather/dot main (verified logic == R3 tt_main2) ----
    {
        const int tid = g * 256 + t;                       // 2 elems per thread
        const v4i* Xr = (const v4i*)(X + (size_t)tid * 64);
        v4i c[16];
        #pragma unroll
        for (int q = 0; q < 16; q++) c[q] = __builtin_nontemporal_load(Xr + q);

        unsigned key[4] = { 0u, 0u, 0u, 0u };              // p0, s0, p1, s1
        #pragma unroll
        for (int q = 0; q < 16; q++) {
            const unsigned nib = ((unsigned)(c[q].x & 1) << 3) | ((unsigned)(c[q].y & 1) << 2) |
                                 ((unsigned)(c[q].z & 1) << 1) | (unsigned)(c[q].w & 1);
            key[q >> 2] = (key[q >> 2] << 4) | nib;
        }

        const v4f* v0 = (const v4f*)(ws + OFF_V16 + (size_t)key[0] * 16);
        const v4f* w0 = (const v4f*)(ws + OFF_W16 + (size_t)key[1] * 16);
        const v4f* v1 = (const v4f*)(ws + OFF_V16 + (size_t)key[2] * 16);
        const v4f* w1 = (const v4f*)(ws + OFF_W16 + (size_t)key[3] * 16);

        v4f acc0 = { 0.f, 0.f, 0.f, 0.f }, acc1 = { 0.f, 0.f, 0.f, 0.f };
        #pragma unroll
        for (int k = 0; k < 4; k++) acc0 += v0[k] * w0[k];
        #pragma unroll
        for (int k = 0; k < 4; k++) acc1 += v1[k] * w1[k];

        v2f res;
        res.x = acc0.x + acc0.y + acc0.z + acc0.w;
        res.y = acc1.x + acc1.y + acc1.z + acc1.w;
        __builtin_nontemporal_store(res, (v2f*)(out + (size_t)tid * 2));
    }
}

// ---------------------------------------------------------------------------
// Fallback: direct per-thread chain (only if ws too small).
__global__ __launch_bounds__(256) void tt_direct(const int* __restrict__ X,
                                                 const float* __restrict__ cf,
                                                 const float* __restrict__ cm,
                                                 const float* __restrict__ cl,
                                                 float* __restrict__ out) {
    __shared__ float scm[30 * 16 * 16 * 2];
    for (int i = threadIdx.x; i < 30 * 16 * 16 * 2; i += blockDim.x) scm[i] = cm[i];
    __syncthreads();
    const int b = blockIdx.x * blockDim.x + threadIdx.x;
    if (b >= BATCH) return;
    const int* xr = X + (size_t)b * TT_D;
    float v[R], nv[R];
    const int x0 = xr[0] & 1;
    #pragma unroll
    for (int r = 0; r < R; r++) v[r] = cf[r * 2 + x0];
    for (int i = 1; i <= 30; i++) {
        const int bit = xr[i] & 1;
        const float* M = scm + (i - 1) * 512;
        #pragma unroll
        for (int s2 = 0; s2 < R; s2++) {
            float acc = 0.f;
            #pragma unroll
            for (int r = 0; r < R; r++) acc += v[r] * M[(r * 16 + s2) * 2 + bit];
            nv[s2] = acc;
        }
        #pragma unroll
        for (int s2 = 0; s2 < R; s2++) v[s2] = nv[s2];
    }
    const int xl = xr[31] & 1;
    float acc = 0.f;
    #pragma unroll
    for (int r = 0; r < R; r++) acc += v[r] * cl[r * 2 + xl];
    out[b] = acc;
}

extern "C" void kernel_launch(void* const* d_in, const int* in_sizes, int n_in,
                              void* d_out, int out_size, void* d_ws, size_t ws_size,
                              hipStream_t stream) {
    const int* X = (const int*)d_in[0];
    const float* cf = (const float*)d_in[1];
    const float* cm = (const float*)d_in[2];
    const float* cl = (const float*)d_in[3];
    float* out = (float*)d_out;

    if (ws_size >= (size_t)WS_FLOATS * sizeof(float)) {
        float* ws = (float*)d_ws;
        // zero barrier state (cnt, gen) — ws is poisoned 0xAA before every call
        hipMemsetAsync((void*)(ws + OFF_BAR), 0, 64, stream);
        tt_all<<<NBLK, 256, 0, stream>>>(X, cf, cm, cl, ws, out);
    } else {
        tt_direct<<<(BATCH + 255) / 256, 256, 0, stream>>>(X, cf, cm, cl, out);
    }
}

// Round 6
// 123.343 us; speedup vs baseline: 2.5151x; 2.5151x over previous
//
#include <hip/hip_runtime.h>

// TensorTrain: out[b] = first(x0) . M0(x1) . ... . M29(x30) . last(x31)
// R=16, D=32, B=262144, bits in {0,1}.
// Meet-in-the-middle: V16[p=x0..x15] row-vector, W16[s=x16..x31] col-vector,
// out = V16[p] . W16[s].
// R6: NO grid barrier (R5's spin barrier caused an agent-scope buffer_inv
// storm: 244 us at 0.8% VALUBusy). Build is embarrassingly parallel:
// one block per table slice, all inputs staged in LDS, slice written
// contiguously. Two plain kernels; the kernel boundary is the sync.

#define R 16
#define TT_D 32
#define BATCH 262144

// workspace layout, in floats: only the two final tables.
// V16 is stored BYTE-SWAPPED: entry (p) lives at ((p&255)<<8)|(p>>8), so the
// build block for lo-byte l writes a contiguous 16 KB run. W16 is natural.
#define OFF_V16  0
#define OFF_W16  1048576
#define WS_FLOATS 2097152               // 8 MB

typedef int   v4i __attribute__((ext_vector_type(4)));
typedef float v4f __attribute__((ext_vector_type(4)));

// LDS offsets (floats) inside one 8480-float block
#define L_TM   0        // 8 cores for the ping-pong chain: [c][x][s][k], k contig (4096)
#define L_TC   4096     // 7 cores for per-thread chains (3584)
                        //   V side: [c][x][s][r], r contig (column access)
                        //   W side: [c][x][r][k], k contig (row access)
#define L_PING 7680     // 256
#define L_PONG 7936     // 256
#define L_PQT  8192     // 256: V side: P8 transposed [s][r]; W side: Q8 natural [r][k]
#define L_CV   8448     // 32: cf or cl
#define L_TOT  8480

// ---------------------------------------------------------------------------
// Build kernel: 512 blocks.
//   g in [0,256):  V16 slice for lo-byte l=g   (cores 0..14 + cf)
//   g in [256,512): W16 slice for hi-byte h=g-256 (cores 15..29 + cl)
__global__ __launch_bounds__(256) void tt_build(const float* __restrict__ cf,
                                                const float* __restrict__ cm,
                                                const float* __restrict__ cl,
                                                float* __restrict__ ws) {
    __shared__ float sh[L_TOT];
    const int g = blockIdx.x;
    const int t = threadIdx.x;
    const bool isV = (g < 256);
    const int sel = isV ? g : (g - 256);   // l for V side, h for W side

    // ---- stage cores into LDS ----
    // Tm: 8 ping-pong cores (V: 7..14, W: 15..22), layout [c][x][s][k]:
    //   Tm[((c*2+x)<<8) + (s<<4) + k] = M[k][s]  (k = global row index r)
    {
        const float* src = cm + (isV ? 7 : 15) * 512;
        for (int i = t; i < 4096; i += 256) {
            const int c = i >> 9, j = i & 511;
            const int r = j >> 5, s = (j >> 1) & 15, x = j & 1;
            sh[L_TM + (((c << 1) + x) << 8) + (s << 4) + r] = src[i];
        }
    }
    // Tc: 7 per-thread-chain cores (V: 0..6 as [c][x][s][r]; W: 23..29 as [c][x][r][s])
    {
        const float* src = cm + (isV ? 0 : 23) * 512;
        for (int i = t; i < 3584; i += 256) {
            const int c = i >> 9, j = i & 511;
            const int r = j >> 5, s = (j >> 1) & 15, x = j & 1;
            const int dst = isV ? ((s << 4) + r) : ((r << 4) + s);
            sh[L_TC + (((c << 1) + x) << 8) + dst] = src[i];
        }
    }
    if (t < 32) sh[L_CV + t] = isV ? cf[t] : cl[t];
    __syncthreads();

    // ---- ping-pong 8-core matrix product (P8[sel] or Q8[sel]) ----
    // thread t = (r<<4)|s computes element [r][s]; cur buffers are row-major [r][k].
    {
        const int r = t >> 4, s = t & 15;
        float acc = sh[L_TM + (((sel >> 7) & 1) << 8) + (s << 4) + r];  // M_base[r][s](bit7)
        float* cur = sh + L_PING;
        float* nxt = sh + L_PONG;
        cur[t] = acc;                                   // t == r*16+s, row-major
        for (int j = 1; j < 8; j++) {
            __syncthreads();
            const int bb = (sel >> (7 - j)) & 1;
            const float* M = sh + L_TM + (((j << 1) + bb) << 8) + (s << 4);  // [k] contig
            const float* cr = cur + (r << 4);
            acc = 0.f;
            #pragma unroll
            for (int k = 0; k < 16; k++) acc += cr[k] * M[k];
            nxt[t] = acc;
            float* tmp = cur; cur = nxt; nxt = tmp;
        }
        // store product for the final multiply:
        // V side transposed [s][r] (column access); W side natural [r][k].
        sh[L_PQT + (isV ? ((s << 4) + r) : (r << 4) + s)] = acc;
    }
    __syncthreads();

    // ---- per-thread vector chain + final multiply + contiguous slice store ----
    if (isV) {
        const int h = t;                                 // entry index (bits x0..x7)
        float v[16], nv[16];
        const int b0 = (h >> 7) & 1;
        #pragma unroll
        for (int s = 0; s < 16; s++) v[s] = sh[L_CV + s * 2 + b0];
        for (int j = 0; j < 7; j++) {                    // cores 0..6
            const int bb = (h >> (6 - j)) & 1;
            const float* Tj = sh + L_TC + (((j << 1) + bb) << 8);  // [s][r], r contig
            #pragma unroll
            for (int s = 0; s < 16; s++) {
                const float* col = Tj + (s << 4);
                float a = 0.f;
                #pragma unroll
                for (int r = 0; r < 16; r++) a += v[r] * col[r];
                nv[s] = a;
            }
            #pragma unroll
            for (int s = 0; s < 16; s++) v[s] = nv[s];
        }
        // o[s] = sum_r V8[h][r] * P8[r][s]   (P8 stored [s][r])
        float o[16];
        #pragma unroll
        for (int s = 0; s < 16; s++) {
            const float* col = sh + L_PQT + (s << 4);
            float a = 0.f;
            #pragma unroll
            for (int r = 0; r < 16; r++) a += v[r] * col[r];
            o[s] = a;
        }
        // byte-swapped layout: entry (h<<8)|sel stored at (sel<<8)|h → contiguous
        float* dst = ws + OFF_V16 + ((size_t)((sel << 8) | h) << 4);
        #pragma unroll
        for (int s = 0; s < 16; s++) dst[s] = o[s];
    } else {
        const int l = t;                                 // entry index (bits x24..x31)
        float w[16], nw[16];
        const int bl = l & 1;                            // x31
        #pragma unroll
        for (int r = 0; r < 16; r++) w[r] = sh[L_CV + r * 2 + bl];
        for (int j = 0; j < 7; j++) {                    // cores 29 down to 23 (local 6..0)
            const int cc = 6 - j;
            const int bb = (l >> (1 + j)) & 1;
            const float* Tj = sh + L_TC + (((cc << 1) + bb) << 8);  // [r][k], k contig
            #pragma unroll
            for (int r = 0; r < 16; r++) {
                const float* row = Tj + (r << 4);
                float a = 0.f;
                #pragma unroll
                for (int k = 0; k < 16; k++) a += row[k] * w[k];
                nw[r] = a;
            }
            #pragma unroll
            for (int r = 0; r < 16; r++) w[r] = nw[r];
        }
        // o[r] = sum_k Q8[r][k] * W8[l][k]   (Q8 stored [r][k])
        float o[16];
        #pragma unroll
        for (int r = 0; r < 16; r++) {
            const float* row = sh + L_PQT + (r << 4);
            float a = 0.f;
            #pragma unroll
            for (int k = 0; k < 16; k++) a += row[k] * w[k];
            o[r] = a;
        }
        // natural layout: entry (sel<<8)|l → contiguous
        float* dst = ws + OFF_W16 + ((size_t)((sel << 8) | l) << 4);
        #pragma unroll
        for (int r = 0; r < 16; r++) dst[r] = o[r];
    }
}

// ---------------------------------------------------------------------------
// Gather/dot main: 1024 blocks x 256 threads, 1 batch element per thread
// (R1-proven body). NT X loads / NT out store protect table L2 residency.
__global__ __launch_bounds__(256) void tt_gather(const int* __restrict__ X,
                                                 const float* __restrict__ ws,
                                                 float* __restrict__ out) {
    const int b = blockIdx.x * 256 + threadIdx.x;
    const v4i* Xr = (const v4i*)(X + (size_t)b * TT_D);
    v4i c[8];
    #pragma unroll
    for (int q = 0; q < 8; q++) c[q] = __builtin_nontemporal_load(Xr + q);

    unsigned p = 0, s = 0;
    #pragma unroll
    for (int q = 0; q < 4; q++) {
        p = (p << 4) | ((unsigned)(c[q].x & 1) << 3) | ((unsigned)(c[q].y & 1) << 2) |
            ((unsigned)(c[q].z & 1) << 1) | (unsigned)(c[q].w & 1);
    }
    #pragma unroll
    for (int q = 4; q < 8; q++) {
        s = (s << 4) | ((unsigned)(c[q].x & 1) << 3) | ((unsigned)(c[q].y & 1) << 2) |
            ((unsigned)(c[q].z & 1) << 1) | (unsigned)(c[q].w & 1);
    }

    const unsigned vi = ((p & 255u) << 8) | (p >> 8);    // V16 stored byte-swapped
    const v4f* v = (const v4f*)(ws + OFF_V16 + (size_t)vi * 16);
    const v4f* w = (const v4f*)(ws + OFF_W16 + (size_t)s * 16);

    v4f acc = { 0.f, 0.f, 0.f, 0.f };
    #pragma unroll
    for (int k = 0; k < 4; k++) acc += v[k] * w[k];
    __builtin_nontemporal_store(acc.x + acc.y + acc.z + acc.w, out + b);
}

// ---------------------------------------------------------------------------
// Fallback: direct per-thread chain (only if ws too small).
__global__ __launch_bounds__(256) void tt_direct(const int* __restrict__ X,
                                                 const float* __restrict__ cf,
                                                 const float* __restrict__ cm,
                                                 const float* __restrict__ cl,
                                                 float* __restrict__ out) {
    __shared__ float scm[30 * 16 * 16 * 2];
    for (int i = threadIdx.x; i < 30 * 16 * 16 * 2; i += blockDim.x) scm[i] = cm[i];
    __syncthreads();
    const int b = blockIdx.x * blockDim.x + threadIdx.x;
    if (b >= BATCH) return;
    const int* xr = X + (size_t)b * TT_D;
    float v[R], nv[R];
    const int x0 = xr[0] & 1;
    #pragma unroll
    for (int r = 0; r < R; r++) v[r] = cf[r * 2 + x0];
    for (int i = 1; i <= 30; i++) {
        const int bit = xr[i] & 1;
        const float* M = scm + (i - 1) * 512;
        #pragma unroll
        for (int s2 = 0; s2 < R; s2++) {
            float acc = 0.f;
            #pragma unroll
            for (int r = 0; r < R; r++) acc += v[r] * M[(r * 16 + s2) * 2 + bit];
            nv[s2] = acc;
        }
        #pragma unroll
        for (int s2 = 0; s2 < R; s2++) v[s2] = nv[s2];
    }
    const int xl = xr[31] & 1;
    float acc = 0.f;
    #pragma unroll
    for (int r = 0; r < R; r++) acc += v[r] * cl[r * 2 + xl];
    out[b] = acc;
}

extern "C" void kernel_launch(void* const* d_in, const int* in_sizes, int n_in,
                              void* d_out, int out_size, void* d_ws, size_t ws_size,
                              hipStream_t stream) {
    const int* X = (const int*)d_in[0];
    const float* cf = (const float*)d_in[1];
    const float* cm = (const float*)d_in[2];
    const float* cl = (const float*)d_in[3];
    float* out = (float*)d_out;

    if (ws_size >= (size_t)WS_FLOATS * sizeof(float)) {
        float* ws = (float*)d_ws;
        tt_build<<<512, 256, 0, stream>>>(cf, cm, cl, ws);
        tt_gather<<<1024, 256, 0, stream>>>(X, ws, out);
    } else {
        tt_direct<<<(BATCH + 255) / 256, 256, 0, stream>>>(X, cf, cm, cl, out);
    }
}